// Round 1
// 107.623 us; speedup vs baseline: 1.0131x; 1.0131x over previous
//
#include <hip/hip_runtime.h>

// out[n,s,d] = sum_{l=0..7} weight[l, x[n,s,l], d]
// N=8, S=2048, L=8, K=1024, D=1024
//
// Single fused kernel, direct fp32 gather (no fp16 conversion pass):
//  - Removes 48 MiB of HBM traffic (32 read + 16 write) and one launch.
//  - XCD-partitioned: chunk = blockIdx&7 -> each XCD's 4 MiB fp32 d-slice
//    stays resident in its private L2; gather reads are L2 hits after the
//    compulsory 32 MiB first touch.
//  - Per thread: 4 rows x 8 levels = 32 independent 16 B loads in flight,
//    4 f32x4 accumulators, nontemporal fp32 stores (no RFO on out).

#define NS      (8 * 2048)
#define LVL     8
#define KK      1024
#define DD      1024
#define NCH     8                 // d-chunks (== XCD count)
#define DCH     (DD / NCH)        // 128 floats per chunk
#define ROWSPB  32                // ns rows per block
#define THREADS 256

typedef float f32x4 __attribute__((ext_vector_type(4)));

__global__ __launch_bounds__(THREADS, 4) void multi_embedding_f32_kernel(
    const int* __restrict__ x,          // (N*S, L) int32
    const float* __restrict__ w,        // (L, K, D) fp32
    float* __restrict__ out)            // (N*S, D) fp32
{
    const int chunk = blockIdx.x & (NCH - 1);      // -> XCD id (round-robin)
    const int nsg   = blockIdx.x >> 3;
    const int tid   = threadIdx.x;
    const int ns0   = nsg * ROWSPB;

    // Stage 32 rows x 8 levels of indices: 256 ints, one 4B load per thread.
    __shared__ int sidx[ROWSPB * LVL];
    sidx[tid] = x[(size_t)ns0 * LVL + tid];
    __syncthreads();

    const int lane = tid & 31;        // 32 lanes x 4 floats = 128 = DCH
    const int rg   = tid >> 5;        // 0..7 row-groups

    const float* wl = w + (size_t)chunk * DCH + (size_t)lane * 4;

    const int rows[4] = { rg, rg + 8, rg + 16, rg + 24 };

    f32x4 acc[4];
#pragma unroll
    for (int r = 0; r < 4; ++r) {
        const int idx0 = sidx[rows[r] * LVL + 0];
        acc[r] = *reinterpret_cast<const f32x4*>(wl + ((size_t)idx0 << 10));
    }
#pragma unroll
    for (int l = 1; l < LVL; ++l) {
#pragma unroll
        for (int r = 0; r < 4; ++r) {
            const int idx = sidx[rows[r] * LVL + l];
            acc[r] += *reinterpret_cast<const f32x4*>(
                wl + ((size_t)((l << 10) + idx) << 10));
        }
    }

#pragma unroll
    for (int r = 0; r < 4; ++r) {
        float* o = out + (size_t)(ns0 + rows[r]) * DD
                 + (size_t)chunk * DCH + (size_t)lane * 4;
        __builtin_nontemporal_store(acc[r], reinterpret_cast<f32x4*>(o));
    }
}

extern "C" void kernel_launch(void* const* d_in, const int* in_sizes, int n_in,
                              void* d_out, int out_size, void* d_ws, size_t ws_size,
                              hipStream_t stream) {
    const int*   x = (const int*)d_in[0];
    const float* w = (const float*)d_in[1];
    float*     out = (float*)d_out;

    // (NS/ROWSPB) groups * NCH chunks = 512 * 8 = 4096 blocks
    multi_embedding_f32_kernel<<<dim3((NS / ROWSPB) * NCH), dim3(THREADS), 0, stream>>>(x, w, out);
}